// Round 1
// baseline (102.493 us; speedup 1.0000x reference)
//
#include <hip/hip_runtime.h>

// Problem constants (match reference)
#define BATCH  8192
#define KK     25
#define LL     25
#define BN_EPS 1e-5f
#define PREPB  32              // prep blocks (256 rows each) — R6 proven
#define LG     5               // l-values per eval block
#define NLG    (LL / LG)
#define VB     8               // batch elements per thread in eval (R11: 4->8)
#define EVT    128             // eval block threads (R11: 256->128, grid stays 1000 blocks)
#define WSP    80              // per-l LDS packed-weight slab stride (dwords)

// Workspace layout (float offsets):
#define WS_PART   0                         // [PREPB][50] partial sums
#define WS_SCALE  1600                      // (fallback path only)
#define WS_SHIFT  1632
#define WS_XT     2048                      // [LL][BATCH] transposed x
#define WS_FP     (WS_XT + LL * BATCH)      // [NLG][KK][BATCH] partial outputs
#define WS_END    (WS_FP + NLG * KK * BATCH)

// Packed fp16 pair in one VGPR. R10: weights stored as (w[2p], w[2p+1]) —
// two DIFFERENT weights per dword — and broadcast into both batch lanes via
// VOP3P op_sel modifiers. R11: the weight ds_read stream is per-WAVE and
// independent of VB, so VB=8 (half the waves, 128-thread blocks to keep the
// 1000-block grid) halves total LDS-pipe work at unchanged VALU work.
typedef _Float16 h2v __attribute__((ext_vector_type(2)));

// d.lane = fma(a.lane, w.lo, c.lane)
static __device__ __forceinline__ h2v pk_fma_wl(h2v a, h2v w, h2v c) {
    h2v d;
    asm("v_pk_fma_f16 %0, %1, %2, %3 op_sel:[0,0,0] op_sel_hi:[1,0,1]"
        : "=v"(d) : "v"(a), "v"(w), "v"(c));
    return d;
}
// d.lane = fma(a.lane, w.hi, c.lane)
static __device__ __forceinline__ h2v pk_fma_wh(h2v a, h2v w, h2v c) {
    h2v d;
    asm("v_pk_fma_f16 %0, %1, %2, %3 op_sel:[0,1,0] op_sel_hi:[1,1,1]"
        : "=v"(d) : "v"(a), "v"(w), "v"(c));
    return d;
}
// d.lane = fma(a.lane, w.lo, c.lo)
static __device__ __forceinline__ h2v pk_fma_wl_cl(h2v a, h2v w, h2v c) {
    h2v d;
    asm("v_pk_fma_f16 %0, %1, %2, %3 op_sel:[0,0,0] op_sel_hi:[1,0,0]"
        : "=v"(d) : "v"(a), "v"(w), "v"(c));
    return d;
}
// d.lane = fma(a.lane, w.lo, c.hi)
static __device__ __forceinline__ h2v pk_fma_wl_ch(h2v a, h2v w, h2v c) {
    h2v d;
    asm("v_pk_fma_f16 %0, %1, %2, %3 op_sel:[0,0,1] op_sel_hi:[1,0,1]"
        : "=v"(d) : "v"(a), "v"(w), "v"(c));
    return d;
}
// d.lane = fma(a.lane, w.hi, c.hi)
static __device__ __forceinline__ h2v pk_fma_wh_ch(h2v a, h2v w, h2v c) {
    h2v d;
    asm("v_pk_fma_f16 %0, %1, %2, %3 op_sel:[0,1,1] op_sel_hi:[1,1,1]"
        : "=v"(d) : "v"(a), "v"(w), "v"(c));
    return d;
}
static __device__ __forceinline__ h2v pk_max(h2v a, h2v b) {
    h2v d;
    asm("v_pk_max_f16 %0, %1, %2" : "=v"(d) : "v"(a), "v"(b));
    return d;
}
static __device__ __forceinline__ h2v pack2(float a, float b) {
    h2v r; r.x = (_Float16)a; r.y = (_Float16)b; return r;
}

// ---------------------------------------------------------------------------
// prep: coalesced read of x chunk -> LDS; coalesced transposed write to xT;
// per-column partial sum/sumsq (no atomics). 32 blocks x 256 rows. (R6 verbatim)
// ---------------------------------------------------------------------------
__global__ __launch_bounds__(256) void prep_kernel(
    const float* __restrict__ x,
    float* __restrict__ xT,
    float* __restrict__ part)
{
    __shared__ float xs[256 * LL];          // 25.6 KB
    const int tid = threadIdx.x;
    const int b0  = blockIdx.x * 256;

    const float* src = x + (size_t)b0 * LL;
    #pragma unroll
    for (int i = 0; i < LL; ++i)
        xs[i * 256 + tid] = src[i * 256 + tid];
    __syncthreads();

    #pragma unroll
    for (int l = 0; l < LL; ++l)
        xT[l * BATCH + b0 + tid] = xs[tid * LL + l];

    float s = 0.f, s2 = 0.f;
    if (tid < 200) {
        const int l = tid % LL;
        const int g = tid / LL;
        #pragma unroll
        for (int r = 0; r < 32; ++r) {
            const float v = xs[(g * 32 + r) * LL + l];
            s += v;
            s2 = fmaf(v, v, s2);
        }
    }
    __syncthreads();
    if (tid < 200) { xs[tid] = s; xs[200 + tid] = s2; }
    __syncthreads();

    if (tid < 50) {
        const int c = tid;
        float t = 0.f;
        if (c < LL) {
            #pragma unroll
            for (int g = 0; g < 8; ++g) t += xs[g * LL + c];
        } else {
            #pragma unroll
            for (int g = 0; g < 8; ++g) t += xs[200 + g * LL + (c - LL)];
        }
        part[blockIdx.x * 50 + c] = t;
    }
}

// ---------------------------------------------------------------------------
// eval (R11): R10's packed-pair fp16 structure with VB=8 / 128-thread blocks.
// Grid stays (8, 25, 5) = 1000 blocks; total waves 4000 -> 2000, so the
// wave-uniform 74-dword/l-iter weight ds_read stream (the R9/R10-identified
// LDS-pipe bottleneck) is issued half as many times chip-wide. Total VALU
// work (MAC floor: 126 MACs/elem, 2 per v_pk_fma_f16) is unchanged.
// LDS slab per j (stride WSP=80 dwords):
//   [0:4) w1p [4:8) b1p [8:40) w2p [40:44) b2p [44:68) w3p [68:71) b3p [71:74) w4p
//   pair p of array A holds (A[2p], A[2p+1]).
// ---------------------------------------------------------------------------
__global__ __launch_bounds__(128) void eval_kernel(
    const float* __restrict__ xT,
    const float* __restrict__ W1, const float* __restrict__ b1,
    const float* __restrict__ W2, const float* __restrict__ b2,
    const float* __restrict__ W3, const float* __restrict__ b3,
    const float* __restrict__ W4, const float* __restrict__ b4,
    const float* __restrict__ alpha,
    const float* __restrict__ part,
    const float* __restrict__ gamma,
    const float* __restrict__ bn_bias,
    float* __restrict__ fp)
{
    __shared__ h2v   wl[LG * WSP];          // 400 dwords = 1.6 KB
    __shared__ float sss[2 * LG];           // scale[5], shift[5] (fp32)
    __shared__ float tmp[2 * LG];

    const int tid = threadIdx.x;            // 0..127
    const int k   = blockIdx.y;
    const int g   = blockIdx.z;
    const int l0  = g * LG;
    const int kl0 = k * LL + l0;
    const int b   = (blockIdx.x * EVT + tid) * VB;

    // ---- stats partial loads issued FIRST so their latency hides under
    //      the weight staging below ----
    float stat_s = 0.f;
    if (tid < 2 * LG) {
        const int col = (tid < LG) ? (l0 + tid) : (LL + l0 + tid - LG);
        #pragma unroll
        for (int i = 0; i < PREPB; ++i)
            stat_s += part[i * 50 + col];
    }

    // ---- stage weights as packed pairs (once per block) ----
    {                                        // w2p: 160 entries, 128 threads
        const int j = tid >> 5, p = tid & 31;
        const float* s = W2 + (kl0 + j) * 64 + 2 * p;
        wl[j * WSP + 8 + p] = pack2(s[0], s[1]);
        if (tid < 32) {
            const int idx = tid + 128;
            const int j2 = idx >> 5, p2 = idx & 31;
            const float* s2 = W2 + (kl0 + j2) * 64 + 2 * p2;
            wl[j2 * WSP + 8 + p2] = pack2(s2[0], s2[1]);
        }
    }
    if (tid < 120) {                         // w3p: 5*24
        const int j = tid / 24, p = tid % 24;
        const float* s = W3 + (kl0 + j) * 48 + 2 * p;
        wl[j * WSP + 44 + p] = pack2(s[0], s[1]);
    }
    if (tid < 20) {                          // w1p, b1p, b2p: 5*4 each
        const int j = tid >> 2, p = tid & 3;
        const float* s1 = W1 + (kl0 + j) * 8 + 2 * p;
        const float* t1 = b1 + (kl0 + j) * 8 + 2 * p;
        const float* t2 = b2 + (kl0 + j) * 8 + 2 * p;
        wl[j * WSP +      p] = pack2(s1[0], s1[1]);
        wl[j * WSP +  4 + p] = pack2(t1[0], t1[1]);
        wl[j * WSP + 40 + p] = pack2(t2[0], t2[1]);
    }
    if (tid < 15) {                          // b3p, w4p: 5*3 each
        const int j = tid / 3, p = tid % 3;
        const float* t3 = b3 + (kl0 + j) * 6 + 2 * p;
        const float* s4 = W4 + (kl0 + j) * 6 + 2 * p;
        wl[j * WSP + 68 + p] = pack2(t3[0], t3[1]);
        wl[j * WSP + 71 + p] = pack2(s4[0], s4[1]);
    }

    if (tid < 2 * LG) tmp[tid] = stat_s;
    __syncthreads();
    if (tid < LG) {
        const float s = tmp[tid], s2 = tmp[LG + tid];
        const float inv_b = 1.f / (float)BATCH;
        const float mean  = s * inv_b;
        const float var   = fmaf(s2, inv_b, -mean * mean);
        const float scale = rsqrtf(var + BN_EPS) * gamma[l0 + tid];
        sss[tid]      = scale;
        sss[LG + tid] = fmaf(-mean, scale, bn_bias[l0 + tid]);
    }
    __syncthreads();

    // ---- compute (packed fp16, op_sel weight broadcast, 4 h2v pairs) ----
    h2v zero2; zero2.x = (_Float16)0.f; zero2.y = (_Float16)0.f;
    float acc[VB] = {0.f, 0.f, 0.f, 0.f, 0.f, 0.f, 0.f, 0.f};

    #pragma unroll
    for (int j = 0; j < LG; ++j) {
        const int l = l0 + j;
        const h2v* w = wl + j * WSP;

        const float scale = sss[j];
        const float shift = sss[LG + j];
        const float a     = alpha[l * KK + k];        // wave-uniform s_load
        const float b4f   = b4[kl0 + j];              // wave-uniform s_load

        const float4 xv0 = *(const float4*)&xT[l * BATCH + b];
        const float4 xv1 = *(const float4*)&xT[l * BATCH + b + 4];
        h2v xn[4];
        xn[0] = pack2(fmaf(xv0.x, scale, shift), fmaf(xv0.y, scale, shift));
        xn[1] = pack2(fmaf(xv0.z, scale, shift), fmaf(xv0.w, scale, shift));
        xn[2] = pack2(fmaf(xv1.x, scale, shift), fmaf(xv1.y, scale, shift));
        xn[3] = pack2(fmaf(xv1.z, scale, shift), fmaf(xv1.w, scale, shift));

        // layer 1: 1 -> 8  (w1p[p]=(w1[2p],w1[2p+1]), b1p same)
        h2v h1[4][8];
        #pragma unroll
        for (int p = 0; p < 4; ++p) {
            const h2v wp = w[p], bp = w[4 + p];
            #pragma unroll
            for (int q = 0; q < 4; ++q) {
                h1[q][2*p]   = pk_max(pk_fma_wl_cl(xn[q], wp, bp), zero2);
                h1[q][2*p+1] = pk_max(pk_fma_wh_ch(xn[q], wp, bp), zero2);
            }
        }

        // layer 2: 8 -> 8  (w2p[i*4+hp]=(w2[i*8+2hp], w2[i*8+2hp+1]))
        h2v h2[4][8];
        #pragma unroll
        for (int i = 0; i < 8; ++i) {
            const h2v bp = w[40 + (i >> 1)];
            const h2v w0 = w[8 + i * 4];
            h2v t[4];
            #pragma unroll
            for (int q = 0; q < 4; ++q) {
                if (i & 1) t[q] = pk_fma_wl_ch(h1[q][0], w0, bp);
                else       t[q] = pk_fma_wl_cl(h1[q][0], w0, bp);
                t[q] = pk_fma_wh(h1[q][1], w0, t[q]);
            }
            #pragma unroll
            for (int hp = 1; hp < 4; ++hp) {
                const h2v wp = w[8 + i * 4 + hp];
                #pragma unroll
                for (int q = 0; q < 4; ++q) {
                    t[q] = pk_fma_wl(h1[q][2*hp],   wp, t[q]);
                    t[q] = pk_fma_wh(h1[q][2*hp+1], wp, t[q]);
                }
            }
            #pragma unroll
            for (int q = 0; q < 4; ++q) h2[q][i] = pk_max(t[q], zero2);
        }

        // layer 3: 8 -> 6  (w3p[jj*4+ip])
        h2v h3[4][6];
        #pragma unroll
        for (int jj = 0; jj < 6; ++jj) {
            const h2v bp = w[68 + (jj >> 1)];
            const h2v w0 = w[44 + jj * 4];
            h2v t[4];
            #pragma unroll
            for (int q = 0; q < 4; ++q) {
                if (jj & 1) t[q] = pk_fma_wl_ch(h2[q][0], w0, bp);
                else        t[q] = pk_fma_wl_cl(h2[q][0], w0, bp);
                t[q] = pk_fma_wh(h2[q][1], w0, t[q]);
            }
            #pragma unroll
            for (int ip = 1; ip < 4; ++ip) {
                const h2v wp = w[44 + jj * 4 + ip];
                #pragma unroll
                for (int q = 0; q < 4; ++q) {
                    t[q] = pk_fma_wl(h2[q][2*ip],   wp, t[q]);
                    t[q] = pk_fma_wh(h2[q][2*ip+1], wp, t[q]);
                }
            }
            #pragma unroll
            for (int q = 0; q < 4; ++q) h3[q][jj] = pk_max(t[q], zero2);
        }

        // layer 4: 6 -> 1 (w4p[jp]=(w4[2jp],w4[2jp+1])), finish in fp32
        h2v fd[4] = {zero2, zero2, zero2, zero2};
        #pragma unroll
        for (int jp = 0; jp < 3; ++jp) {
            const h2v wp = w[71 + jp];
            #pragma unroll
            for (int q = 0; q < 4; ++q) {
                fd[q] = pk_fma_wl(h3[q][2*jp],   wp, fd[q]);
                fd[q] = pk_fma_wh(h3[q][2*jp+1], wp, fd[q]);
            }
        }
        #pragma unroll
        for (int q = 0; q < 4; ++q) {
            acc[2*q]   = fmaf(a, b4f + (float)fd[q].x, acc[2*q]);
            acc[2*q+1] = fmaf(a, b4f + (float)fd[q].y, acc[2*q+1]);
        }
    }

    float4 o0 = {acc[0], acc[1], acc[2], acc[3]};
    float4 o1 = {acc[4], acc[5], acc[6], acc[7]};
    float* dst = &fp[(g * KK + k) * BATCH + b];
    *(float4*)dst       = o0;
    *(float4*)(dst + 4) = o1;
}

// ---------------------------------------------------------------------------
// reduce: out[b][k] = beta[k] + sum_g fp[g][k][b]; coalesced loads. (R6 verbatim)
// ---------------------------------------------------------------------------
__global__ __launch_bounds__(256) void reduce_kernel(
    const float* __restrict__ fp,
    const float* __restrict__ beta,
    float* __restrict__ out)
{
    const int tid = threadIdx.x;
    const int k   = blockIdx.y;
    const int b   = blockIdx.x * 256 + tid;

    float acc = beta[k];
    #pragma unroll
    for (int g = 0; g < NLG; ++g)
        acc += fp[(g * KK + k) * BATCH + b];
    out[(size_t)b * KK + k] = acc;
}

// ---------------------------------------------------------------------------
// fallbacks (small workspace) — fp32, proven correct.
// ---------------------------------------------------------------------------
__device__ __forceinline__ float mlp_eval(
    float xn, int kl,
    const float* __restrict__ W1, const float* __restrict__ b1,
    const float* __restrict__ W2, const float* __restrict__ b2,
    const float* __restrict__ W3, const float* __restrict__ b3,
    const float* __restrict__ W4, const float* __restrict__ b4)
{
    const float* w1  = W1 + kl * 8;
    const float* bb1 = b1 + kl * 8;
    float h1[8];
    #pragma unroll
    for (int h = 0; h < 8; ++h)
        h1[h] = fmaxf(fmaf(xn, w1[h], bb1[h]), 0.f);

    const float* w2  = W2 + kl * 64;
    const float* bb2 = b2 + kl * 8;
    float h2v_[8];
    #pragma unroll
    for (int i = 0; i < 8; ++i) {
        float t = bb2[i];
        #pragma unroll
        for (int h = 0; h < 8; ++h)
            t = fmaf(h1[h], w2[i * 8 + h], t);
        h2v_[i] = fmaxf(t, 0.f);
    }

    const float* w3  = W3 + kl * 48;
    const float* bb3 = b3 + kl * 6;
    float h3[6];
    #pragma unroll
    for (int j = 0; j < 6; ++j) {
        float t = bb3[j];
        #pragma unroll
        for (int i = 0; i < 8; ++i)
            t = fmaf(h2v_[i], w3[j * 8 + i], t);
        h3[j] = fmaxf(t, 0.f);
    }

    const float* w4 = W4 + kl * 6;
    float f = b4[kl];
    #pragma unroll
    for (int j = 0; j < 6; ++j)
        f = fmaf(h3[j], w4[j], f);
    return f;
}

__global__ __launch_bounds__(256) void stats_small_kernel(
    const float* __restrict__ x,
    const float* __restrict__ gamma,
    const float* __restrict__ bn_bias,
    float* __restrict__ ws)
{
    const int l   = blockIdx.x;
    const int tid = threadIdx.x;

    float s = 0.f, s2 = 0.f;
    for (int b = tid; b < BATCH; b += 256) {
        float v = x[b * LL + l];
        s  += v;
        s2  = fmaf(v, v, s2);
    }
    for (int off = 32; off > 0; off >>= 1) {
        s  += __shfl_down(s,  off);
        s2 += __shfl_down(s2, off);
    }
    __shared__ float red[8];
    const int wave = tid >> 6;
    if ((tid & 63) == 0) { red[wave] = s; red[4 + wave] = s2; }
    __syncthreads();
    if (tid == 0) {
        s  = red[0] + red[1] + red[2] + red[3];
        s2 = red[4] + red[5] + red[6] + red[7];
        const float inv_b = 1.f / (float)BATCH;
        float mean = s * inv_b;
        float var  = fmaf(s2, inv_b, -mean * mean);
        float scale = rsqrtf(var + BN_EPS) * gamma[l];
        ws[WS_SCALE + l] = scale;
        ws[WS_SHIFT + l] = fmaf(-mean, scale, bn_bias[l]);
    }
}

__global__ __launch_bounds__(256) void mlp_lds_direct_kernel(
    const float* __restrict__ x,
    const float* __restrict__ W1, const float* __restrict__ b1,
    const float* __restrict__ W2, const float* __restrict__ b2,
    const float* __restrict__ W3, const float* __restrict__ b3,
    const float* __restrict__ W4, const float* __restrict__ b4,
    const float* __restrict__ alpha, const float* __restrict__ beta,
    const float* __restrict__ ws,
    float* __restrict__ out)
{
    __shared__ float xs[256 * LL];
    const int tid = threadIdx.x;
    const int k   = blockIdx.y;
    const int b0  = blockIdx.x * 256;

    const float* xsrc = x + (size_t)b0 * LL;
    #pragma unroll
    for (int i = 0; i < LL; ++i)
        xs[i * 256 + tid] = xsrc[i * 256 + tid];
    __syncthreads();

    float acc = beta[k];
    for (int l = 0; l < LL; ++l) {
        const int kl = k * LL + l;
        const float xn = fmaf(xs[tid * LL + l], ws[WS_SCALE + l], ws[WS_SHIFT + l]);
        const float f  = mlp_eval(xn, kl, W1, b1, W2, b2, W3, b3, W4, b4);
        acc = fmaf(alpha[l * KK + k], f, acc);
    }
    out[(size_t)(b0 + tid) * KK + k] = acc;
}

extern "C" void kernel_launch(void* const* d_in, const int* in_sizes, int n_in,
                              void* d_out, int out_size, void* d_ws, size_t ws_size,
                              hipStream_t stream) {
    const float* x       = (const float*)d_in[0];
    const float* gamma   = (const float*)d_in[1];
    const float* bn_bias = (const float*)d_in[2];
    const float* W1      = (const float*)d_in[3];
    const float* b1      = (const float*)d_in[4];
    const float* W2      = (const float*)d_in[5];
    const float* b2      = (const float*)d_in[6];
    const float* W3      = (const float*)d_in[7];
    const float* b3      = (const float*)d_in[8];
    const float* W4      = (const float*)d_in[9];
    const float* b4      = (const float*)d_in[10];
    const float* alpha   = (const float*)d_in[11];
    const float* beta    = (const float*)d_in[12];

    float* out = (float*)d_out;
    float* ws  = (float*)d_ws;
    float* xT  = ws + WS_XT;
    float* fp  = ws + WS_FP;

    const bool fast = ws_size >= (size_t)WS_END * sizeof(float);

    if (fast) {
        prep_kernel<<<dim3(PREPB), dim3(256), 0, stream>>>(x, xT, ws + WS_PART);
        eval_kernel<<<dim3(BATCH / (EVT * VB), KK, NLG), dim3(EVT), 0, stream>>>(
            xT, W1, b1, W2, b2, W3, b3, W4, b4, alpha,
            ws + WS_PART, gamma, bn_bias, fp);
        reduce_kernel<<<dim3(BATCH / 256, KK), dim3(256), 0, stream>>>(fp, beta, out);
    } else {
        stats_small_kernel<<<dim3(LL), dim3(256), 0, stream>>>(x, gamma, bn_bias, ws);
        mlp_lds_direct_kernel<<<dim3(BATCH / 256, KK), dim3(256), 0, stream>>>(
            x, W1, b1, W2, b2, W3, b3, W4, b4, alpha, beta, ws, out);
    }
}